// Round 11
// baseline (235.640 us; speedup 1.0000x reference)
//
#include <hip/hip_runtime.h>
#include <hip/hip_fp16.h>

#define EPS 1e-5f

typedef __attribute__((ext_vector_type(8))) _Float16 half8;
typedef __attribute__((ext_vector_type(4))) float float4v;

// ---------------------------------------------------------------------------
// Generalized batched TN GEMM: C[m][n] = sum_k A[k][m] * B[k][n]
// (only used for the ZstT contraction now). KS==1, TC=__half path.
// ---------------------------------------------------------------------------
template<int BM, int BN, int BK, int TM, int TN, int KS, typename TA, typename TC>
__global__ __launch_bounds__((BM/TM)*(BN/TN))
void gemm_tn(const TA* __restrict__ A, const float* __restrict__ B,
             TC* __restrict__ C, int K,
             int lda, int ldb, int ldc,
             int divA, long long bsAd, int modA, long long bsAm,
             int divB, long long bsBd, int modB, long long bsBm,
             int divC, long long bsCd, int modC, long long bsCm)
{
    constexpr int T  = (BM/TM)*(BN/TN);
    constexpr int HM = TM/2, HN = TN/2;
    __shared__ float As[BK][BM];
    __shared__ float Bs[BK][BN];

    const int tid = threadIdx.x;
    const int z = blockIdx.z;
    const int mtile = blockIdx.y / KS;
    const int ks = blockIdx.y % KS;
    const int n0 = blockIdx.x * BN;
    const int m0 = mtile * BM;
    A += (long long)(z / divA) * bsAd + (long long)(z % modA) * bsAm;
    B += (long long)(z / divB) * bsBd + (long long)(z % modB) * bsBm;
    C += (long long)(z / divC) * bsCd + (long long)(z % modC) * bsCm;

    const int tx = tid % (BN/TN);
    const int ty = tid / (BN/TN);

    float acc[TM][TN] = {};

    const int kc = K / KS;
    const int kBeg = ks * kc;

    for (int k0 = kBeg; k0 < kBeg + kc; k0 += BK) {
#pragma unroll
        for (int idx = tid * 4; idx < BK * BM; idx += T * 4) {
            int rr = idx / BM, cc = idx % BM;
            *(float4*)&As[rr][cc] = *(const float4*)(A + (long long)(k0 + rr) * lda + m0 + cc);
        }
#pragma unroll
        for (int idx = tid * 4; idx < BK * BN; idx += T * 4) {
            int rr = idx / BN, cc = idx % BN;
            *(float4*)&Bs[rr][cc] = *(const float4*)(B + (long long)(k0 + rr) * ldb + n0 + cc);
        }
        __syncthreads();
#pragma unroll
        for (int kk = 0; kk < BK; kk++) {
            float a[TM], b[TN];
#pragma unroll
            for (int u = 0; u < HM; u++) {
                a[u]      = As[kk][ty * HM + u];
                a[HM + u] = As[kk][BM / 2 + ty * HM + u];
            }
#pragma unroll
            for (int v = 0; v < HN; v++) {
                b[v]      = Bs[kk][tx * HN + v];
                b[HN + v] = Bs[kk][BN / 2 + tx * HN + v];
            }
#pragma unroll
            for (int u = 0; u < TM; u++)
#pragma unroll
                for (int v = 0; v < TN; v++)
                    acc[u][v] += a[u] * b[v];
        }
        __syncthreads();
    }

#pragma unroll
    for (int u = 0; u < TM; u++) {
        int rl = (u < HM) ? ty * HM + u : BM / 2 + ty * HM + (u - HM);
        TC* cr = C + (long long)(m0 + rl) * ldc + n0;
        if constexpr (sizeof(TC) == 2) {
#pragma unroll
            for (int v = 0; v < HN; v++) {
                cr[tx * HN + v]          = __float2half(acc[u][v]);
                cr[BN / 2 + tx * HN + v] = __float2half(acc[u][HN + v]);
            }
        } else {
#pragma unroll
            for (int v = 0; v < HN; v++) {
                cr[tx * HN + v] = acc[u][v];
                cr[BN / 2 + tx * HN + v] = acc[u][HN + v];
            }
        }
    }
}

// ---------------------------------------------------------------------------
// Mega-prep (flat grid 1064, branch per block):
//  bid <1024         : MFMA Gram partials Gpart[ks][z] (plain stores)
//  1024..1031        : WvT fp32 transpose
//  1032..1039        : WkT16 fp16 transpose
//  1040..1047        : Wo16[o][i] fp16
//  1048..1063        : GW (from Wk) / GQ (from Wq) split-K8 VALU + wks/wqs sums
// ---------------------------------------------------------------------------
__global__ __launch_bounds__(256)
void prep_k(const float* __restrict__ emb, const float* __restrict__ Wq,
            const float* __restrict__ Wk, const float* __restrict__ Wv,
            const float* __restrict__ Wo, float* __restrict__ Gpart,
            float* __restrict__ WvT, __half* __restrict__ WkT16,
            __half* __restrict__ Wo16, float* __restrict__ GQ,
            float* __restrict__ GW, float* __restrict__ wqs,
            float* __restrict__ wks)
{
    __shared__ __align__(16) char smem[18432];
    const int tid = threadIdx.x;
    const int bid = blockIdx.x;

    if (bid < 1024) {
        // ---- MFMA Gram partial ----
        __half (*As)[72] = (__half(*)[72])smem;
        __half (*Bs)[72] = (__half(*)[72])(smem + 9216);
        const int ks = bid >> 7;
        const int z  = bid & 127;            // pair = (d*8+b)*8+b'
        const int d  = z >> 6;
        const int bp = z & 7;
        const float* Xq  = emb + (long long)(z >> 3) * 131072;
        const float* Xkv = emb + (long long)(1 - d) * 1048576 + (long long)bp * 131072;

        const int lane = tid & 63, w = tid >> 6, q = lane >> 4, l16 = lane & 15;
        const int tok = tid & 63;
        const int cg  = w * 16;

        float4v acc[4];
#pragma unroll
        for (int nt = 0; nt < 4; nt++) acc[nt] = (float4v)0.f;

        for (int t0 = ks * 256; t0 < ks * 256 + 256; t0 += 64) {
            const float* q4 = Xq  + (long long)(t0 + tok) * 64 + cg;
            const float* k4 = Xkv + (long long)(t0 + tok) * 64 + cg;
#pragma unroll
            for (int j = 0; j < 4; j++) {
                float4 v = *(const float4*)(q4 + j * 4);
                As[cg + j * 4 + 0][tok] = __float2half(v.x);
                As[cg + j * 4 + 1][tok] = __float2half(v.y);
                As[cg + j * 4 + 2][tok] = __float2half(v.z);
                As[cg + j * 4 + 3][tok] = __float2half(v.w);
                float4 u = *(const float4*)(k4 + j * 4);
                Bs[cg + j * 4 + 0][tok] = __float2half(u.x);
                Bs[cg + j * 4 + 1][tok] = __float2half(u.y);
                Bs[cg + j * 4 + 2][tok] = __float2half(u.z);
                Bs[cg + j * 4 + 3][tok] = __float2half(u.w);
            }
            __syncthreads();
#pragma unroll
            for (int kc = 0; kc < 64; kc += 32) {
                half8 af = *(const half8*)&As[w * 16 + l16][kc + q * 8];
                half8 bf[4];
#pragma unroll
                for (int nt = 0; nt < 4; nt++)
                    bf[nt] = *(const half8*)&Bs[nt * 16 + l16][kc + q * 8];
#pragma unroll
                for (int nt = 0; nt < 4; nt++)
                    acc[nt] = __builtin_amdgcn_mfma_f32_16x16x32_f16(af, bf[nt], acc[nt], 0, 0, 0);
            }
            __syncthreads();
        }

        float* Gz = Gpart + (long long)ks * 524288 + (long long)z * 4096;
#pragma unroll
        for (int nt = 0; nt < 4; nt++)
#pragma unroll
            for (int t = 0; t < 4; t++) {
                int m = w * 16 + q * 4 + t;
                Gz[m * 64 + nt * 16 + l16] = acc[nt][t];
            }
    } else if (bid < 1048) {
        // ---- transposes: WvT (fp32), WkT16 (fp16), Wo16 (fp16) ----
        float (*t)[65] = (float(*)[65])smem;
        const int which = (bid - 1024) >> 3;     // 0 WvT, 1 WkT16, 2 Wo16
        const int c0 = ((bid - 1024) & 7) * 64;
        const int c = tid & 63, r4 = tid >> 6;
        if (which < 2) {
            const float* in = which == 0 ? Wv : Wk;
#pragma unroll
            for (int rr = r4; rr < 64; rr += 4)
                t[rr][c] = in[rr * 512 + c0 + c];
            __syncthreads();
#pragma unroll
            for (int rr = r4; rr < 64; rr += 4) {
                float v = t[c][rr];
                if (which == 0) WvT[(c0 + rr) * 64 + c] = v;
                else            WkT16[(c0 + rr) * 64 + c] = __float2half(v);
            }
        } else {
#pragma unroll
            for (int rr = r4; rr < 64; rr += 4)
                t[rr][c] = Wo[(c0 + rr) * 64 + c];
            __syncthreads();
#pragma unroll
            for (int rr = r4; rr < 64; rr += 4)
                Wo16[rr * 512 + c0 + c] = __float2half(t[c][rr]);
        }
    } else {
        // ---- GW/GQ Grams direct from Wk/Wq, split-K8, + row-sum atomics ----
        float (*Wl)[68] = (float(*)[68])smem;
        const int t2 = bid - 1048;
        const int which = t2 >> 3;               // 0 GW(Wk), 1 GQ(Wq)
        const int i0 = (t2 & 7) * 64;
        const float* W = which ? Wq : Wk;
        float* Gout = which ? GQ : GW;
        float* wsum = which ? wqs : wks;
#pragma unroll
        for (int it = 0; it < 4; it++) {
            int e = tid + it * 256;              // 0..1023
            int cc = e >> 4, i4 = (e & 15) * 4;
            *(float4*)&Wl[cc][i4] = *(const float4*)(W + cc * 512 + i0 + i4);
        }
        __syncthreads();
        if (tid < 64) {
            float s = 0.f;
#pragma unroll
            for (int j = 0; j < 64; j++) s += Wl[tid][j];
            atomicAdd(&wsum[tid], s);
        }
        const int cr = tid >> 2, cg = (tid & 3) * 16;
        float p[16] = {};
        for (int k = 0; k < 64; k++) {
            float a = Wl[cr][k];
#pragma unroll
            for (int j = 0; j < 16; j++) p[j] += a * Wl[cg + j][k];
        }
#pragma unroll
        for (int j = 0; j < 16; j++)
            atomicAdd(&Gout[cr * 64 + cg + j], p[j]);
    }
}

// ---------------------------------------------------------------------------
// stats2e: 8-way reduce Gpart -> Gs (LDS), analytic IN stats, then E16
// production (E16[pair][i][c'] = sum_c Wq[c][i]*G[c][c'], fp16) reusing the
// GQs LDS buffer as Wq staging. grid 128 pairs, block 256.
// ---------------------------------------------------------------------------
__global__ __launch_bounds__(256)
void stats2e_k(const float* __restrict__ Gpart, const float* __restrict__ GQ,
               const float* __restrict__ GW, const float* __restrict__ wqs,
               const float* __restrict__ wks, float* __restrict__ sums,
               const float* __restrict__ Wq, __half* __restrict__ E16)
{
    __shared__ float Gs[64][68], GQs[64][68], GWs[64][68];
    const int tid = threadIdx.x;
    const int z = blockIdx.x;
    for (int f = tid * 4; f < 4096; f += 1024) {
        float4 g = make_float4(0.f, 0.f, 0.f, 0.f);
#pragma unroll
        for (int s = 0; s < 8; s++) {
            float4 p = *(const float4*)(Gpart + (long long)s * 524288 + (long long)z * 4096 + f);
            g.x += p.x; g.y += p.y; g.z += p.z; g.w += p.w;
        }
        int rr = f >> 6, cc = f & 63;
        *(float4*)&Gs[rr][cc]  = g;
        *(float4*)&GQs[rr][cc] = *(const float4*)(GQ + f);
        *(float4*)&GWs[rr][cc] = *(const float4*)(GW + f);
    }
    __syncthreads();
    const int r = tid >> 2;
    const int c0 = (tid & 3) * 16;
    float p1[16] = {}, p2[16] = {};
    for (int k = 0; k < 64; k++) {
        float gq = GQs[r][k], g = Gs[r][k];
#pragma unroll
        for (int j = 0; j < 16; j++) {
            p1[j] += gq * Gs[k][c0 + j];
            p2[j] += g  * GWs[k][c0 + j];
        }
    }
    float s2 = 0.f;
#pragma unroll
    for (int j = 0; j < 16; j++) s2 += p1[j] * p2[j];
    float s1 = 0.f;
    const float wq = wqs[r];
#pragma unroll
    for (int j = 0; j < 16; j++) s1 += wq * Gs[r][c0 + j] * wks[c0 + j];

    const int lane = tid & 63, w = tid >> 6;
#pragma unroll
    for (int off = 32; off; off >>= 1) {
        s1 += __shfl_down(s1, off, 64);
        s2 += __shfl_down(s2, off, 64);
    }
    __shared__ float r1[4], r2[4];
    if (lane == 0) { r1[w] = s1; r2[w] = s2; }
    __syncthreads();
    if (tid == 0) {
        atomicAdd(&sums[(z >> 3) * 2],     r1[0] + r1[1] + r1[2] + r1[3]);
        atomicAdd(&sums[(z >> 3) * 2 + 1], r2[0] + r2[1] + r2[2] + r2[3]);
    }

    // ---- E16 production (reuse GQs as Wq chunk staging) ----
    const int il = tid & 63, cg2 = (tid >> 6) * 16;
    __half* Ez = E16 + (long long)z * 32768;
    for (int chunk = 0; chunk < 8; chunk++) {
        __syncthreads();   // protect previous chunk's reads before overwrite
#pragma unroll
        for (int it = 0; it < 4; it++) {
            int e = tid + it * 256;
            int cc = e >> 4, i4 = (e & 15) * 4;
            *(float4*)&GQs[cc][i4] = *(const float4*)(Wq + cc * 512 + chunk * 64 + i4);
        }
        __syncthreads();
        float a[16] = {};
        for (int c = 0; c < 64; c++) {
            float wv = GQs[c][il];
#pragma unroll
            for (int j = 0; j < 16; j++) a[j] += wv * Gs[c][cg2 + j];
        }
        __half* Ep = Ez + (chunk * 64 + il) * 64 + cg2;
#pragma unroll
        for (int j = 0; j < 16; j += 2)
            *(__half2*)(Ep + j) = __floats2half2_rn(a[j], a[j + 1]);
    }
}

// ---------------------------------------------------------------------------
// MFMA rowsums:  rs[db][i] += sum_ch exp(r * S[i][ch-tile])  (no S store).
// ---------------------------------------------------------------------------
__global__ __launch_bounds__(256)
void mfma_rows(const __half* __restrict__ E16, const __half* __restrict__ WkT16,
               const float* __restrict__ sums, float* __restrict__ rs)
{
    __shared__ __half Es[128][72];
    __shared__ __half Ws[128][72];
    const int tid = threadIdx.x;
    const int z = blockIdx.z;          // pair = db*8 + b'
    const int i0 = blockIdx.y * 128;
    const int ch0 = blockIdx.x * 128;
    const int db = z >> 3;
    const __half* Ez = E16 + (long long)z * 32768;

#pragma unroll
    for (int it = 0; it < 4; it++) {
        int e = tid + it * 256;
        int row = e >> 3, c8 = (e & 7) * 8;
        *(half8*)&Es[row][c8] = *(const half8*)(Ez + (long long)(i0 + row) * 64 + c8);
        *(half8*)&Ws[row][c8] = *(const half8*)(WkT16 + (long long)(ch0 + row) * 64 + c8);
    }
    __syncthreads();

    const int lane = tid & 63;
    const int w = tid >> 6;
    const int q = lane >> 4;
    const int l16 = lane & 15;

    float4v acc[2][8];
#pragma unroll
    for (int a = 0; a < 2; a++)
#pragma unroll
        for (int b = 0; b < 8; b++) acc[a][b] = (float4v)0.f;

#pragma unroll
    for (int kc = 0; kc < 64; kc += 32) {
        half8 af[2], bf[8];
#pragma unroll
        for (int mt = 0; mt < 2; mt++)
            af[mt] = *(const half8*)&Es[w * 32 + mt * 16 + l16][kc + q * 8];
#pragma unroll
        for (int nt = 0; nt < 8; nt++)
            bf[nt] = *(const half8*)&Ws[nt * 16 + l16][kc + q * 8];
#pragma unroll
        for (int mt = 0; mt < 2; mt++)
#pragma unroll
            for (int nt = 0; nt < 8; nt++)
                acc[mt][nt] = __builtin_amdgcn_mfma_f32_16x16x32_f16(af[mt], bf[nt], acc[mt][nt], 0, 0, 0);
    }

    const float inv = 1.f / 2097152.f;
    const float mu  = sums[2 * db] * inv;
    const float var = sums[2 * db + 1] * inv - mu * mu;
    const float rv  = rsqrtf(var + EPS);

    float* rsb = rs + db * 512 + i0 + w * 32;
#pragma unroll
    for (int mt = 0; mt < 2; mt++) {
#pragma unroll
        for (int t = 0; t < 4; t++) {
            const int irow = mt * 16 + q * 4 + t;
            float p = 0.f;
#pragma unroll
            for (int nt = 0; nt < 8; nt++) p += __expf(rv * acc[mt][nt][t]);
            p += __shfl_xor(p, 1, 16);
            p += __shfl_xor(p, 2, 16);
            p += __shfl_xor(p, 4, 16);
            p += __shfl_xor(p, 8, 16);
            if (l16 == 0) atomicAdd(&rsb[irow], p);
        }
    }
}

// ---------------------------------------------------------------------------
// Fused S-recompute + exp(+softmax-normalize) + U2 contraction.
// ---------------------------------------------------------------------------
__global__ __launch_bounds__(256)
void mfma_su2(const __half* __restrict__ E16, const __half* __restrict__ WkT16,
              const __half* __restrict__ Wo16, const float* __restrict__ rs,
              const float* __restrict__ sums, float* __restrict__ U2)
{
    __shared__ __half Ws[128][72];
    __shared__ __half Es[64][72];
    __shared__ __half Wos[64][72];
    __shared__ __half Pt[64][136];
    __shared__ float rsS[64];

    const int tid = threadIdx.x;
    const int jt = blockIdx.x;
    const int db = blockIdx.y;
    const int bp = jt >> 2;
    const int ch0 = (jt & 3) * 128;
    const int z = db * 8 + bp;

    const __half* Ez = E16 + (long long)z * 32768;

#pragma unroll
    for (int it = 0; it < 4; it++) {
        int e = tid + it * 256;
        int row = e >> 3, c8 = (e & 7) * 8;
        *(half8*)&Ws[row][c8] = *(const half8*)(WkT16 + (long long)(ch0 + row) * 64 + c8);
    }

    const int lane = tid & 63;
    const int w = tid >> 6;
    const int q = lane >> 4;
    const int l16 = lane & 15;

    const float inv = 1.f / 2097152.f;
    const float mu  = sums[2 * db] * inv;
    const float var = sums[2 * db + 1] * inv - mu * mu;
    const float rv  = rsqrtf(var + EPS);

    float4v u2acc[2][4];
#pragma unroll
    for (int a = 0; a < 2; a++)
#pragma unroll
        for (int b = 0; b < 4; b++) u2acc[a][b] = (float4v)0.f;

    const int lrow = tid >> 2;
    const int lc8 = (tid & 3) * 16;

    for (int i0 = 0; i0 < 512; i0 += 64) {
        *(half8*)&Es[lrow][lc8]      = *(const half8*)(Ez + (long long)(i0 + lrow) * 64 + lc8);
        *(half8*)&Es[lrow][lc8 + 8]  = *(const half8*)(Ez + (long long)(i0 + lrow) * 64 + lc8 + 8);
        *(half8*)&Wos[lrow][lc8]     = *(const half8*)(Wo16 + (long long)lrow * 512 + i0 + lc8);
        *(half8*)&Wos[lrow][lc8 + 8] = *(const half8*)(Wo16 + (long long)lrow * 512 + i0 + lc8 + 8);
        if (tid < 64) rsS[tid] = rs[db * 512 + i0 + tid];
        __syncthreads();

        float4v sacc[2][4];
#pragma unroll
        for (int a = 0; a < 2; a++)
#pragma unroll
            for (int b = 0; b < 4; b++) sacc[a][b] = (float4v)0.f;
#pragma unroll
        for (int kc = 0; kc < 64; kc += 32) {
            half8 af[2], bf[4];
#pragma unroll
            for (int ct = 0; ct < 2; ct++)
                af[ct] = *(const half8*)&Ws[w * 32 + ct * 16 + l16][kc + q * 8];
#pragma unroll
            for (int it = 0; it < 4; it++)
                bf[it] = *(const half8*)&Es[it * 16 + l16][kc + q * 8];
#pragma unroll
            for (int ct = 0; ct < 2; ct++)
#pragma unroll
                for (int it = 0; it < 4; it++)
                    sacc[ct][it] = __builtin_amdgcn_mfma_f32_16x16x32_f16(af[ct], bf[it], sacc[ct][it], 0, 0, 0);
        }

        float invr[4];
#pragma unroll
        for (int it = 0; it < 4; it++) invr[it] = 4096.0f / rsS[it * 16 + l16];

#pragma unroll
        for (int ct = 0; ct < 2; ct++)
#pragma unroll
            for (int it = 0; it < 4; it++) {
                float e0 = __expf(rv * sacc[ct][it][0]) * invr[it];
                float e1 = __expf(rv * sacc[ct][it][1]) * invr[it];
                float e2 = __expf(rv * sacc[ct][it][2]) * invr[it];
                float e3 = __expf(rv * sacc[ct][it][3]) * invr[it];
                int row = it * 16 + l16;
                int swz = ((row >> 3) & 3) << 4;
                int col = (w * 32 + ct * 16 + q * 4) ^ swz;
                *(__half2*)&Pt[row][col]     = __floats2half2_rn(e0, e1);
                *(__half2*)&Pt[row][col + 2] = __floats2half2_rn(e2, e3);
            }
        __syncthreads();

#pragma unroll
        for (int kc = 0; kc < 64; kc += 32) {
            half8 af2[2], bf2[4];
#pragma unroll
            for (int mt = 0; mt < 2; mt++) {
                const int cph = (w * 32 + mt * 16 + l16) ^ (q << 4);
#pragma unroll
                for (int t = 0; t < 8; t++)
                    af2[mt][t] = Pt[kc + q * 8 + t][cph];
            }
#pragma unroll
            for (int ot = 0; ot < 4; ot++)
                bf2[ot] = *(const half8*)&Wos[ot * 16 + l16][kc + q * 8];
#pragma unroll
            for (int mt = 0; mt < 2; mt++)
#pragma unroll
                for (int ot = 0; ot < 4; ot++)
                    u2acc[mt][ot] = __builtin_amdgcn_mfma_f32_16x16x32_f16(af2[mt], bf2[ot], u2acc[mt][ot], 0, 0, 0);
        }
        __syncthreads();
    }

    const float sc = 1.f / 4096.f;
    float* Ud = U2 + (long long)db * 262144;
#pragma unroll
    for (int mt = 0; mt < 2; mt++)
#pragma unroll
        for (int ot = 0; ot < 4; ot++)
#pragma unroll
            for (int t = 0; t < 4; t++) {
                int j = bp * 512 + ch0 + w * 32 + mt * 16 + q * 4 + t;
                Ud[(long long)j * 64 + ot * 16 + l16] = u2acc[mt][ot][t] * sc;
            }
}

// ---------------------------------------------------------------------------
// MFMA out:  out[db][n][o] = sum_{bp,c} emb_kv[bp][n][c] * ZstT[db][o][bp*64+c]
// ---------------------------------------------------------------------------
__global__ __launch_bounds__(256)
void mfma_out(const float* __restrict__ emb, const __half* __restrict__ ZstT,
              float* __restrict__ out)
{
    __shared__ __half Xs[128][72];
    __shared__ __half Bs[64][72];
    const int tid = threadIdx.x;
    const int db = blockIdx.y;
    const int d = db >> 3;
    const int n0 = blockIdx.x * 128;
    const float* Xb = emb + (long long)(1 - d) * 1048576;
    const __half* Bz = ZstT + (long long)db * 32768;

    const int lane = tid & 63, w = tid >> 6, q = lane >> 4, l16 = lane & 15;

    float4v acc[2][4];
#pragma unroll
    for (int a = 0; a < 2; a++)
#pragma unroll
        for (int b = 0; b < 4; b++) acc[a][b] = (float4v)0.f;

    for (int bp = 0; bp < 8; bp++) {
        const float* src = Xb + (long long)bp * 131072 + (long long)n0 * 64;
#pragma unroll
        for (int it = 0; it < 8; it++) {
            int e = (tid + it * 256) * 4;
            int row = e >> 6, col = e & 63;
            float4 v = *(const float4*)(src + (long long)row * 64 + col);
            *(__half2*)&Xs[row][col]     = __floats2half2_rn(v.x, v.y);
            *(__half2*)&Xs[row][col + 2] = __floats2half2_rn(v.z, v.w);
        }
        {
            int o = tid >> 2, c8 = (tid & 3) * 16;
            *(half8*)&Bs[o][c8]     = *(const half8*)(Bz + o * 512 + bp * 64 + c8);
            *(half8*)&Bs[o][c8 + 8] = *(const half8*)(Bz + o * 512 + bp * 64 + c8 + 8);
        }
        __syncthreads();
#pragma unroll
        for (int kc = 0; kc < 64; kc += 32) {
            half8 af[2], bf[4];
#pragma unroll
            for (int mt = 0; mt < 2; mt++)
                af[mt] = *(const half8*)&Xs[w * 32 + mt * 16 + l16][kc + q * 8];
#pragma unroll
            for (int ot = 0; ot < 4; ot++)
                bf[ot] = *(const half8*)&Bs[ot * 16 + l16][kc + q * 8];
#pragma unroll
            for (int mt = 0; mt < 2; mt++)
#pragma unroll
                for (int ot = 0; ot < 4; ot++)
                    acc[mt][ot] = __builtin_amdgcn_mfma_f32_16x16x32_f16(af[mt], bf[ot], acc[mt][ot], 0, 0, 0);
        }
        __syncthreads();
    }

    float* Od = out + (long long)db * 131072;
#pragma unroll
    for (int mt = 0; mt < 2; mt++)
#pragma unroll
        for (int ot = 0; ot < 4; ot++)
#pragma unroll
            for (int t = 0; t < 4; t++) {
                int n = n0 + w * 32 + mt * 16 + q * 4 + t;
                Od[(long long)n * 64 + ot * 16 + l16] = acc[mt][ot][t];
            }
}

// ---------------------------------------------------------------------------
// Workspace (float offsets):
//   WvT @0:32768
//   zeroed @32768: rs 8192 | sums @40960:32 | GW @40992:4096 | GQ @45088:4096
//                  wqs @49184:64 | wks @49248:64    (memset 16544 floats)
//   Gpart @49312: 4194304 -> ends 4243616
//   E16 (half) @4243616: 4194304 halves -> ends 6340768
//   WkT16 (half) @6340768: 32768 halves -> ends 6357152
//   Wo16 (half) @6357152: 32768 halves -> ends 6373536
//   U2 @6373536: 4194304 -> ends 10567840
//   ZstT (half) @10567840: 524288 halves -> ends 10829984
// ---------------------------------------------------------------------------
extern "C" void kernel_launch(void* const* d_in, const int* in_sizes, int n_in,
                              void* d_out, int out_size, void* d_ws, size_t ws_size,
                              hipStream_t stream)
{
    const float* emb = (const float*)d_in[0];
    const float* Wq  = (const float*)d_in[1];
    const float* Wk  = (const float*)d_in[2];
    const float* Wv  = (const float*)d_in[3];
    const float* Wo  = (const float*)d_in[4];
    float* out = (float*)d_out;
    float* ws  = (float*)d_ws;

    float* WvT   = ws;
    float* zero0 = ws + 32768;
    float* rs    = ws + 32768;
    float* sums  = ws + 40960;
    float* GW    = ws + 40992;
    float* GQ    = ws + 45088;
    float* wqs   = ws + 49184;
    float* wks   = ws + 49248;
    float* Gpart = ws + 49312;
    __half* E16   = (__half*)(ws + 4243616);
    __half* WkT16 = (__half*)(ws + 6340768);
    __half* Wo16  = (__half*)(ws + 6357152);
    float* U2    = ws + 6373536;
    __half* ZstT  = (__half*)(ws + 10567840);

    hipMemsetAsync(zero0, 0, 16544 * sizeof(float), stream);

    // Gram partials + weight prep + GQ/GW + wqs/wks, one dispatch
    prep_k<<<1064, 256, 0, stream>>>(emb, Wq, Wk, Wv, Wo, Gpart, WvT, WkT16,
                                     Wo16, GQ, GW, wqs, wks);

    // reduce Gpart 8->1 (in LDS) + analytic IN stats + E16 production
    stats2e_k<<<128, 256, 0, stream>>>(Gpart, GQ, GW, wqs, wks, sums, Wq, E16);

    // rs[db][i] = sum_j exp(r * S[i][j])   (MFMA, no S store)
    mfma_rows<<<dim3(4, 4, 128), 256, 0, stream>>>(E16, WkT16, sums, rs);

    // U2[db][j][o] = sum_i attn[i][j] * Wo[i][o]   (fused recompute, MFMA)
    mfma_su2<<<dim3(32, 16), 256, 0, stream>>>(E16, WkT16, Wo16, rs, sums, U2);

    // ZstT[db][o][bp*64+c] = sum_ch U2[db][bp*512+ch][o] * WvT[ch][c]
    gemm_tn<64, 64, 16, 4, 4, 1, float, __half><<<dim3(1, 1, 128), 256, 0, stream>>>(
        U2, WvT, ZstT, 512, 64, 64, 512,
        8, 262144LL, 8, 32768LL,
        1, 0LL, 1, 0LL,
        8, 32768LL, 8, 64LL);

    // out[db][n][o] = sum_k emb_kv * ZstT   (MFMA f16, fp32 out)
    mfma_out<<<dim3(16, 16), 256, 0, stream>>>(emb, ZstT, out);
}

// Round 12
// 215.452 us; speedup vs baseline: 1.0937x; 1.0937x over previous
//
#include <hip/hip_runtime.h>
#include <hip/hip_fp16.h>

#define EPS 1e-5f

typedef __attribute__((ext_vector_type(8))) _Float16 half8;
typedef __attribute__((ext_vector_type(4))) float float4v;

// ---------------------------------------------------------------------------
// Generalized batched TN GEMM: C[m][n] = sum_k A[k][m] * B[k][n]
// Used for E16 production and the ZstT contraction. KS==1 plain stores;
// TC=__half converts scalar-wise.
// ---------------------------------------------------------------------------
template<int BM, int BN, int BK, int TM, int TN, typename TA, typename TC>
__global__ __launch_bounds__((BM/TM)*(BN/TN))
void gemm_tn(const TA* __restrict__ A, const float* __restrict__ B,
             TC* __restrict__ C, int K,
             int lda, int ldb, int ldc,
             int divA, long long bsAd, int modA, long long bsAm,
             int divB, long long bsBd, int modB, long long bsBm,
             int divC, long long bsCd, int modC, long long bsCm)
{
    constexpr int T  = (BM/TM)*(BN/TN);
    constexpr int HM = TM/2, HN = TN/2;
    __shared__ float As[BK][BM];
    __shared__ float Bs[BK][BN];

    const int tid = threadIdx.x;
    const int z = blockIdx.z;
    const int n0 = blockIdx.x * BN;
    const int m0 = blockIdx.y * BM;
    A += (long long)(z / divA) * bsAd + (long long)(z % modA) * bsAm;
    B += (long long)(z / divB) * bsBd + (long long)(z % modB) * bsBm;
    C += (long long)(z / divC) * bsCd + (long long)(z % modC) * bsCm;

    const int tx = tid % (BN/TN);
    const int ty = tid / (BN/TN);

    float acc[TM][TN] = {};

    for (int k0 = 0; k0 < K; k0 += BK) {
#pragma unroll
        for (int idx = tid * 4; idx < BK * BM; idx += T * 4) {
            int rr = idx / BM, cc = idx % BM;
            *(float4*)&As[rr][cc] = *(const float4*)(A + (long long)(k0 + rr) * lda + m0 + cc);
        }
#pragma unroll
        for (int idx = tid * 4; idx < BK * BN; idx += T * 4) {
            int rr = idx / BN, cc = idx % BN;
            *(float4*)&Bs[rr][cc] = *(const float4*)(B + (long long)(k0 + rr) * ldb + n0 + cc);
        }
        __syncthreads();
#pragma unroll
        for (int kk = 0; kk < BK; kk++) {
            float a[TM], b[TN];
#pragma unroll
            for (int u = 0; u < HM; u++) {
                a[u]      = As[kk][ty * HM + u];
                a[HM + u] = As[kk][BM / 2 + ty * HM + u];
            }
#pragma unroll
            for (int v = 0; v < HN; v++) {
                b[v]      = Bs[kk][tx * HN + v];
                b[HN + v] = Bs[kk][BN / 2 + tx * HN + v];
            }
#pragma unroll
            for (int u = 0; u < TM; u++)
#pragma unroll
                for (int v = 0; v < TN; v++)
                    acc[u][v] += a[u] * b[v];
        }
        __syncthreads();
    }

#pragma unroll
    for (int u = 0; u < TM; u++) {
        int rl = (u < HM) ? ty * HM + u : BM / 2 + ty * HM + (u - HM);
        TC* cr = C + (long long)(m0 + rl) * ldc + n0;
        if constexpr (sizeof(TC) == 2) {
#pragma unroll
            for (int v = 0; v < HN; v++) {
                cr[tx * HN + v]          = __float2half(acc[u][v]);
                cr[BN / 2 + tx * HN + v] = __float2half(acc[u][HN + v]);
            }
        } else {
#pragma unroll
            for (int v = 0; v < HN; v++) {
                cr[tx * HN + v] = acc[u][v];
                cr[BN / 2 + tx * HN + v] = acc[u][HN + v];
            }
        }
    }
}

// ---------------------------------------------------------------------------
// Mega-prep (flat grid 1064, branch per block), NO atomics / NO pre-zeroing:
//  bid <1024   : MFMA Gram partials Gpart[ks][z] (plain stores)
//  1024..1031  : WvT fp32 transpose
//  1032..1039  : WkT16 fp16 transpose
//  1040..1047  : Wo16[o][i] fp16
//  1048..1063  : GW/GQ partial Grams (plain per-slice stores) + wsum partials
// ---------------------------------------------------------------------------
__global__ __launch_bounds__(256)
void prep_k(const float* __restrict__ emb, const float* __restrict__ Wq,
            const float* __restrict__ Wk, const float* __restrict__ Wv,
            const float* __restrict__ Wo, float* __restrict__ Gpart,
            float* __restrict__ WvT, __half* __restrict__ WkT16,
            __half* __restrict__ Wo16, float* __restrict__ GWQpart,
            float* __restrict__ wsp)
{
    __shared__ __align__(16) char smem[18432];
    const int tid = threadIdx.x;
    const int bid = blockIdx.x;

    if (bid < 1024) {
        __half (*As)[72] = (__half(*)[72])smem;
        __half (*Bs)[72] = (__half(*)[72])(smem + 9216);
        const int ks = bid >> 7;
        const int z  = bid & 127;            // pair = (d*8+b)*8+b'
        const int d  = z >> 6;
        const int bp = z & 7;
        const float* Xq  = emb + (long long)(z >> 3) * 131072;
        const float* Xkv = emb + (long long)(1 - d) * 1048576 + (long long)bp * 131072;

        const int lane = tid & 63, w = tid >> 6, q = lane >> 4, l16 = lane & 15;
        const int tok = tid & 63;
        const int cg  = w * 16;

        float4v acc[4];
#pragma unroll
        for (int nt = 0; nt < 4; nt++) acc[nt] = (float4v)0.f;

        for (int t0 = ks * 256; t0 < ks * 256 + 256; t0 += 64) {
            const float* q4 = Xq  + (long long)(t0 + tok) * 64 + cg;
            const float* k4 = Xkv + (long long)(t0 + tok) * 64 + cg;
#pragma unroll
            for (int j = 0; j < 4; j++) {
                float4 v = *(const float4*)(q4 + j * 4);
                As[cg + j * 4 + 0][tok] = __float2half(v.x);
                As[cg + j * 4 + 1][tok] = __float2half(v.y);
                As[cg + j * 4 + 2][tok] = __float2half(v.z);
                As[cg + j * 4 + 3][tok] = __float2half(v.w);
                float4 u = *(const float4*)(k4 + j * 4);
                Bs[cg + j * 4 + 0][tok] = __float2half(u.x);
                Bs[cg + j * 4 + 1][tok] = __float2half(u.y);
                Bs[cg + j * 4 + 2][tok] = __float2half(u.z);
                Bs[cg + j * 4 + 3][tok] = __float2half(u.w);
            }
            __syncthreads();
#pragma unroll
            for (int kc = 0; kc < 64; kc += 32) {
                half8 af = *(const half8*)&As[w * 16 + l16][kc + q * 8];
                half8 bf[4];
#pragma unroll
                for (int nt = 0; nt < 4; nt++)
                    bf[nt] = *(const half8*)&Bs[nt * 16 + l16][kc + q * 8];
#pragma unroll
                for (int nt = 0; nt < 4; nt++)
                    acc[nt] = __builtin_amdgcn_mfma_f32_16x16x32_f16(af, bf[nt], acc[nt], 0, 0, 0);
            }
            __syncthreads();
        }

        float* Gz = Gpart + (long long)ks * 524288 + (long long)z * 4096;
#pragma unroll
        for (int nt = 0; nt < 4; nt++)
#pragma unroll
            for (int t = 0; t < 4; t++) {
                int m = w * 16 + q * 4 + t;
                Gz[m * 64 + nt * 16 + l16] = acc[nt][t];
            }
    } else if (bid < 1048) {
        float (*t)[65] = (float(*)[65])smem;
        const int which = (bid - 1024) >> 3;     // 0 WvT, 1 WkT16, 2 Wo16
        const int c0 = ((bid - 1024) & 7) * 64;
        const int c = tid & 63, r4 = tid >> 6;
        if (which < 2) {
            const float* in = which == 0 ? Wv : Wk;
#pragma unroll
            for (int rr = r4; rr < 64; rr += 4)
                t[rr][c] = in[rr * 512 + c0 + c];
            __syncthreads();
#pragma unroll
            for (int rr = r4; rr < 64; rr += 4) {
                float v = t[c][rr];
                if (which == 0) WvT[(c0 + rr) * 64 + c] = v;
                else            WkT16[(c0 + rr) * 64 + c] = __float2half(v);
            }
        } else {
#pragma unroll
            for (int rr = r4; rr < 64; rr += 4)
                t[rr][c] = Wo[(c0 + rr) * 64 + c];
            __syncthreads();
#pragma unroll
            for (int rr = r4; rr < 64; rr += 4)
                Wo16[rr * 512 + c0 + c] = __float2half(t[c][rr]);
        }
    } else {
        // GW (slices 0..7, from Wk) / GQ (slices 8..15, from Wq) partials
        float (*Wl)[68] = (float(*)[68])smem;
        const int t2 = bid - 1048;
        const int which = t2 >> 3;               // 0 -> Wk/GW, 1 -> Wq/GQ
        const int sl = t2 & 7;
        const int i0 = sl * 64;
        const float* W = which ? Wq : Wk;
        float* Gout = GWQpart + (long long)(which * 8 + sl) * 4096;
#pragma unroll
        for (int it = 0; it < 4; it++) {
            int e = tid + it * 256;
            int cc = e >> 4, i4 = (e & 15) * 4;
            *(float4*)&Wl[cc][i4] = *(const float4*)(W + cc * 512 + i0 + i4);
        }
        __syncthreads();
        if (tid < 64) {
            float s = 0.f;
#pragma unroll
            for (int j = 0; j < 64; j++) s += Wl[tid][j];
            wsp[(which * 8 + sl) * 64 + tid] = s;
        }
        const int cr = tid >> 2, cg = (tid & 3) * 16;
        float p[16] = {};
        for (int k = 0; k < 64; k++) {
            float a = Wl[cr][k];
#pragma unroll
            for (int j = 0; j < 16; j++) p[j] += a * Wl[cg + j][k];
        }
#pragma unroll
        for (int j = 0; j < 16; j++)
            Gout[cr * 64 + cg + j] = p[j];
    }
}

// ---------------------------------------------------------------------------
// stats2: 8-way reduce Gpart -> Gs (write Gred), reduce GW/GQ/wsum partials,
// analytic IN stats -> per-pair sums2 (plain stores, no atomics).
// grid 128 pairs, block 256.
// ---------------------------------------------------------------------------
__global__ __launch_bounds__(256)
void stats2_k(const float* __restrict__ Gpart, const float* __restrict__ GWQpart,
              const float* __restrict__ wsp, float* __restrict__ Gred,
              float* __restrict__ sums2)
{
    __shared__ float Gs[64][68], GQs[64][68], GWs[64][68];
    __shared__ float wqsS[64], wksS[64];
    const int tid = threadIdx.x;
    const int z = blockIdx.x;
    for (int f = tid * 4; f < 4096; f += 1024) {
        float4 g = make_float4(0.f, 0.f, 0.f, 0.f);
        float4 gw = g, gq = g;
#pragma unroll
        for (int s = 0; s < 8; s++) {
            float4 p = *(const float4*)(Gpart + (long long)s * 524288 + (long long)z * 4096 + f);
            g.x += p.x; g.y += p.y; g.z += p.z; g.w += p.w;
            float4 w1 = *(const float4*)(GWQpart + (long long)s * 4096 + f);
            gw.x += w1.x; gw.y += w1.y; gw.z += w1.z; gw.w += w1.w;
            float4 q1 = *(const float4*)(GWQpart + (long long)(8 + s) * 4096 + f);
            gq.x += q1.x; gq.y += q1.y; gq.z += q1.z; gq.w += q1.w;
        }
        *(float4*)(Gred + (long long)z * 4096 + f) = g;
        int rr = f >> 6, cc = f & 63;
        *(float4*)&Gs[rr][cc]  = g;
        *(float4*)&GWs[rr][cc] = gw;
        *(float4*)&GQs[rr][cc] = gq;
    }
    if (tid < 64) {
        float a = 0.f, b = 0.f;
#pragma unroll
        for (int s = 0; s < 8; s++) {
            b += wsp[s * 64 + tid];          // Wk sums
            a += wsp[(8 + s) * 64 + tid];    // Wq sums
        }
        wqsS[tid] = a; wksS[tid] = b;
    }
    __syncthreads();
    const int r = tid >> 2;
    const int c0 = (tid & 3) * 16;
    float p1[16] = {}, p2[16] = {};
    for (int k = 0; k < 64; k++) {
        float gq = GQs[r][k], g = Gs[r][k];
#pragma unroll
        for (int j = 0; j < 16; j++) {
            p1[j] += gq * Gs[k][c0 + j];
            p2[j] += g  * GWs[k][c0 + j];
        }
    }
    float s2 = 0.f;
#pragma unroll
    for (int j = 0; j < 16; j++) s2 += p1[j] * p2[j];
    float s1 = 0.f;
    const float wq = wqsS[r];
#pragma unroll
    for (int j = 0; j < 16; j++) s1 += wq * Gs[r][c0 + j] * wksS[c0 + j];

    const int lane = tid & 63, w = tid >> 6;
#pragma unroll
    for (int off = 32; off; off >>= 1) {
        s1 += __shfl_down(s1, off, 64);
        s2 += __shfl_down(s2, off, 64);
    }
    __shared__ float r1[4], r2[4];
    if (lane == 0) { r1[w] = s1; r2[w] = s2; }
    __syncthreads();
    if (tid == 0) {
        sums2[z * 2]     = r1[0] + r1[1] + r1[2] + r1[3];
        sums2[z * 2 + 1] = r2[0] + r2[1] + r2[2] + r2[3];
    }
}

__device__ __forceinline__ float rv_from(const float* sums2, int db)
{
    float s1 = 0.f, s2 = 0.f;
#pragma unroll
    for (int p = 0; p < 8; p++) {
        s1 += sums2[(db * 8 + p) * 2];
        s2 += sums2[(db * 8 + p) * 2 + 1];
    }
    const float inv = 1.f / 2097152.f;
    float mu = s1 * inv;
    float var = s2 * inv - mu * mu;
    return rsqrtf(var + EPS);
}

// ---------------------------------------------------------------------------
// MFMA rowsums: rsp[(db*512+i)*32 + bp*4 + chTile] = partial row sums of
// exp(r*S) (plain stores, no atomics, no zero-init).
// ---------------------------------------------------------------------------
__global__ __launch_bounds__(256)
void mfma_rows(const __half* __restrict__ E16, const __half* __restrict__ WkT16,
               const float* __restrict__ sums2, float* __restrict__ rsp)
{
    __shared__ __half Es[128][72];
    __shared__ __half Ws[128][72];
    const int tid = threadIdx.x;
    const int z = blockIdx.z;          // pair = db*8 + b'
    const int i0 = blockIdx.y * 128;
    const int ch0 = blockIdx.x * 128;
    const int db = z >> 3;
    const int bp = z & 7;
    const __half* Ez = E16 + (long long)z * 32768;

#pragma unroll
    for (int it = 0; it < 4; it++) {
        int e = tid + it * 256;
        int row = e >> 3, c8 = (e & 7) * 8;
        *(half8*)&Es[row][c8] = *(const half8*)(Ez + (long long)(i0 + row) * 64 + c8);
        *(half8*)&Ws[row][c8] = *(const half8*)(WkT16 + (long long)(ch0 + row) * 64 + c8);
    }
    __syncthreads();

    const int lane = tid & 63;
    const int w = tid >> 6;
    const int q = lane >> 4;
    const int l16 = lane & 15;

    float4v acc[2][8];
#pragma unroll
    for (int a = 0; a < 2; a++)
#pragma unroll
        for (int b = 0; b < 8; b++) acc[a][b] = (float4v)0.f;

#pragma unroll
    for (int kc = 0; kc < 64; kc += 32) {
        half8 af[2], bf[8];
#pragma unroll
        for (int mt = 0; mt < 2; mt++)
            af[mt] = *(const half8*)&Es[w * 32 + mt * 16 + l16][kc + q * 8];
#pragma unroll
        for (int nt = 0; nt < 8; nt++)
            bf[nt] = *(const half8*)&Ws[nt * 16 + l16][kc + q * 8];
#pragma unroll
        for (int mt = 0; mt < 2; mt++)
#pragma unroll
            for (int nt = 0; nt < 8; nt++)
                acc[mt][nt] = __builtin_amdgcn_mfma_f32_16x16x32_f16(af[mt], bf[nt], acc[mt][nt], 0, 0, 0);
    }

    const float rv = rv_from(sums2, db);
    const int slice = bp * 4 + blockIdx.x;
#pragma unroll
    for (int mt = 0; mt < 2; mt++) {
#pragma unroll
        for (int t = 0; t < 4; t++) {
            const int irow = mt * 16 + q * 4 + t;
            float p = 0.f;
#pragma unroll
            for (int nt = 0; nt < 8; nt++) p += __expf(rv * acc[mt][nt][t]);
            p += __shfl_xor(p, 1, 16);
            p += __shfl_xor(p, 2, 16);
            p += __shfl_xor(p, 4, 16);
            p += __shfl_xor(p, 8, 16);
            if (l16 == 0)
                rsp[(long long)(db * 512 + i0 + w * 32 + irow) * 32 + slice] = p;
        }
    }
}

// ---------------------------------------------------------------------------
// Fused S-recompute + exp(+softmax-normalize) + U2 contraction.
// rsS = 32-slice reduction of rsp (contiguous float4 loads).
// ---------------------------------------------------------------------------
__global__ __launch_bounds__(256)
void mfma_su2(const __half* __restrict__ E16, const __half* __restrict__ WkT16,
              const __half* __restrict__ Wo16, const float* __restrict__ rsp,
              const float* __restrict__ sums2, float* __restrict__ U2)
{
    __shared__ __half Ws[128][72];
    __shared__ __half Es[64][72];
    __shared__ __half Wos[64][72];
    __shared__ __half Pt[64][136];
    __shared__ float rsS[64];

    const int tid = threadIdx.x;
    const int jt = blockIdx.x;
    const int db = blockIdx.y;
    const int bp = jt >> 2;
    const int ch0 = (jt & 3) * 128;
    const int z = db * 8 + bp;

    const __half* Ez = E16 + (long long)z * 32768;

#pragma unroll
    for (int it = 0; it < 4; it++) {
        int e = tid + it * 256;
        int row = e >> 3, c8 = (e & 7) * 8;
        *(half8*)&Ws[row][c8] = *(const half8*)(WkT16 + (long long)(ch0 + row) * 64 + c8);
    }

    const int lane = tid & 63;
    const int w = tid >> 6;
    const int q = lane >> 4;
    const int l16 = lane & 15;

    const float rv = rv_from(sums2, db);

    float4v u2acc[2][4];
#pragma unroll
    for (int a = 0; a < 2; a++)
#pragma unroll
        for (int b = 0; b < 4; b++) u2acc[a][b] = (float4v)0.f;

    const int lrow = tid >> 2;
    const int lc8 = (tid & 3) * 16;

    for (int i0 = 0; i0 < 512; i0 += 64) {
        *(half8*)&Es[lrow][lc8]      = *(const half8*)(Ez + (long long)(i0 + lrow) * 64 + lc8);
        *(half8*)&Es[lrow][lc8 + 8]  = *(const half8*)(Ez + (long long)(i0 + lrow) * 64 + lc8 + 8);
        *(half8*)&Wos[lrow][lc8]     = *(const half8*)(Wo16 + (long long)lrow * 512 + i0 + lc8);
        *(half8*)&Wos[lrow][lc8 + 8] = *(const half8*)(Wo16 + (long long)lrow * 512 + i0 + lc8 + 8);
        if (tid < 64) {
            const float* rp = rsp + (long long)(db * 512 + i0 + tid) * 32;
            float s = 0.f;
#pragma unroll
            for (int j = 0; j < 32; j += 4) {
                float4 v = *(const float4*)(rp + j);
                s += v.x + v.y + v.z + v.w;
            }
            rsS[tid] = s;
        }
        __syncthreads();

        float4v sacc[2][4];
#pragma unroll
        for (int a = 0; a < 2; a++)
#pragma unroll
            for (int b = 0; b < 4; b++) sacc[a][b] = (float4v)0.f;
#pragma unroll
        for (int kc = 0; kc < 64; kc += 32) {
            half8 af[2], bf[4];
#pragma unroll
            for (int ct = 0; ct < 2; ct++)
                af[ct] = *(const half8*)&Ws[w * 32 + ct * 16 + l16][kc + q * 8];
#pragma unroll
            for (int it = 0; it < 4; it++)
                bf[it] = *(const half8*)&Es[it * 16 + l16][kc + q * 8];
#pragma unroll
            for (int ct = 0; ct < 2; ct++)
#pragma unroll
                for (int it = 0; it < 4; it++)
                    sacc[ct][it] = __builtin_amdgcn_mfma_f32_16x16x32_f16(af[ct], bf[it], sacc[ct][it], 0, 0, 0);
        }

        float invr[4];
#pragma unroll
        for (int it = 0; it < 4; it++) invr[it] = 4096.0f / rsS[it * 16 + l16];

#pragma unroll
        for (int ct = 0; ct < 2; ct++)
#pragma unroll
            for (int it = 0; it < 4; it++) {
                float e0 = __expf(rv * sacc[ct][it][0]) * invr[it];
                float e1 = __expf(rv * sacc[ct][it][1]) * invr[it];
                float e2 = __expf(rv * sacc[ct][it][2]) * invr[it];
                float e3 = __expf(rv * sacc[ct][it][3]) * invr[it];
                int row = it * 16 + l16;
                int swz = ((row >> 3) & 3) << 4;
                int col = (w * 32 + ct * 16 + q * 4) ^ swz;
                *(__half2*)&Pt[row][col]     = __floats2half2_rn(e0, e1);
                *(__half2*)&Pt[row][col + 2] = __floats2half2_rn(e2, e3);
            }
        __syncthreads();

#pragma unroll
        for (int kc = 0; kc < 64; kc += 32) {
            half8 af2[2], bf2[4];
#pragma unroll
            for (int mt = 0; mt < 2; mt++) {
                const int cph = (w * 32 + mt * 16 + l16) ^ (q << 4);
#pragma unroll
                for (int t = 0; t < 8; t++)
                    af2[mt][t] = Pt[kc + q * 8 + t][cph];
            }
#pragma unroll
            for (int ot = 0; ot < 4; ot++)
                bf2[ot] = *(const half8*)&Wos[ot * 16 + l16][kc + q * 8];
#pragma unroll
            for (int mt = 0; mt < 2; mt++)
#pragma unroll
                for (int ot = 0; ot < 4; ot++)
                    u2acc[mt][ot] = __builtin_amdgcn_mfma_f32_16x16x32_f16(af2[mt], bf2[ot], u2acc[mt][ot], 0, 0, 0);
        }
        __syncthreads();
    }

    const float sc = 1.f / 4096.f;
    float* Ud = U2 + (long long)db * 262144;
#pragma unroll
    for (int mt = 0; mt < 2; mt++)
#pragma unroll
        for (int ot = 0; ot < 4; ot++)
#pragma unroll
            for (int t = 0; t < 4; t++) {
                int j = bp * 512 + ch0 + w * 32 + mt * 16 + q * 4 + t;
                Ud[(long long)j * 64 + ot * 16 + l16] = u2acc[mt][ot][t] * sc;
            }
}

// ---------------------------------------------------------------------------
// MFMA out:  out[db][n][o] = sum_{bp,c} emb_kv[bp][n][c] * ZstT[db][o][bp*64+c]
// ---------------------------------------------------------------------------
__global__ __launch_bounds__(256)
void mfma_out(const float* __restrict__ emb, const __half* __restrict__ ZstT,
              float* __restrict__ out)
{
    __shared__ __half Xs[128][72];
    __shared__ __half Bs[64][72];
    const int tid = threadIdx.x;
    const int db = blockIdx.y;
    const int d = db >> 3;
    const int n0 = blockIdx.x * 128;
    const float* Xb = emb + (long long)(1 - d) * 1048576;
    const __half* Bz = ZstT + (long long)db * 32768;

    const int lane = tid & 63, w = tid >> 6, q = lane >> 4, l16 = lane & 15;

    float4v acc[2][4];
#pragma unroll
    for (int a = 0; a < 2; a++)
#pragma unroll
        for (int b = 0; b < 4; b++) acc[a][b] = (float4v)0.f;

    for (int bp = 0; bp < 8; bp++) {
        const float* src = Xb + (long long)bp * 131072 + (long long)n0 * 64;
#pragma unroll
        for (int it = 0; it < 8; it++) {
            int e = (tid + it * 256) * 4;
            int row = e >> 6, col = e & 63;
            float4 v = *(const float4*)(src + (long long)row * 64 + col);
            *(__half2*)&Xs[row][col]     = __floats2half2_rn(v.x, v.y);
            *(__half2*)&Xs[row][col + 2] = __floats2half2_rn(v.z, v.w);
        }
        {
            int o = tid >> 2, c8 = (tid & 3) * 16;
            *(half8*)&Bs[o][c8]     = *(const half8*)(Bz + o * 512 + bp * 64 + c8);
            *(half8*)&Bs[o][c8 + 8] = *(const half8*)(Bz + o * 512 + bp * 64 + c8 + 8);
        }
        __syncthreads();
#pragma unroll
        for (int kc = 0; kc < 64; kc += 32) {
            half8 af[2], bf[4];
#pragma unroll
            for (int mt = 0; mt < 2; mt++)
                af[mt] = *(const half8*)&Xs[w * 32 + mt * 16 + l16][kc + q * 8];
#pragma unroll
            for (int ot = 0; ot < 4; ot++)
                bf[ot] = *(const half8*)&Bs[ot * 16 + l16][kc + q * 8];
#pragma unroll
            for (int mt = 0; mt < 2; mt++)
#pragma unroll
                for (int ot = 0; ot < 4; ot++)
                    acc[mt][ot] = __builtin_amdgcn_mfma_f32_16x16x32_f16(af[mt], bf[ot], acc[mt][ot], 0, 0, 0);
        }
        __syncthreads();
    }

    float* Od = out + (long long)db * 131072;
#pragma unroll
    for (int mt = 0; mt < 2; mt++)
#pragma unroll
        for (int ot = 0; ot < 4; ot++)
#pragma unroll
            for (int t = 0; t < 4; t++) {
                int n = n0 + w * 32 + mt * 16 + q * 4 + t;
                Od[(long long)n * 64 + ot * 16 + l16] = acc[mt][ot][t];
            }
}

// ---------------------------------------------------------------------------
// Workspace (float offsets, no zero-init required anywhere):
//   WvT @0:32768
//   Gpart @32768: 4194304 -> 4227072
//   GWQpart @4227072: 65536 -> 4292608   (16 slices x 4096)
//   wsp @4292608: 1024 -> 4293632        (16 slices x 64)
//   sums2 @4293632: 256 -> 4293888       (128 pairs x 2)
//   Gred @4293888: 524288 -> 4818176
//   rsp @4818176: 262144 -> 5080320      ((db*512+i)*32 + slice)
//   E16 (half) @5080320: 4194304 halves -> 7177472
//   WkT16 (half) @7177472 -> 7193856 | Wo16 (half) @7193856 -> 7210240
//   U2 @7210240: 4194304 -> 11404544
//   ZstT (half) @11404544: 524288 halves -> 11666688
// ---------------------------------------------------------------------------
extern "C" void kernel_launch(void* const* d_in, const int* in_sizes, int n_in,
                              void* d_out, int out_size, void* d_ws, size_t ws_size,
                              hipStream_t stream)
{
    const float* emb = (const float*)d_in[0];
    const float* Wq  = (const float*)d_in[1];
    const float* Wk  = (const float*)d_in[2];
    const float* Wv  = (const float*)d_in[3];
    const float* Wo  = (const float*)d_in[4];
    float* out = (float*)d_out;
    float* ws  = (float*)d_ws;

    float* WvT     = ws;
    float* Gpart   = ws + 32768;
    float* GWQpart = ws + 4227072;
    float* wsp     = ws + 4292608;
    float* sums2   = ws + 4293632;
    float* Gred    = ws + 4293888;
    float* rsp     = ws + 4818176;
    __half* E16    = (__half*)(ws + 5080320);
    __half* WkT16  = (__half*)(ws + 7177472);
    __half* Wo16   = (__half*)(ws + 7193856);
    float* U2      = ws + 7210240;
    __half* ZstT   = (__half*)(ws + 11404544);

    // Gram partials + weight prep + GW/GQ/wsum partials, one dispatch
    prep_k<<<1064, 256, 0, stream>>>(emb, Wq, Wk, Wv, Wo, Gpart, WvT, WkT16,
                                     Wo16, GWQpart, wsp);

    // reduce partials + analytic IN stats -> sums2; write Gred
    stats2_k<<<128, 256, 0, stream>>>(Gpart, GWQpart, wsp, Gred, sums2);

    // E16[pair][i][c'] = sum_c Wq[c][i] * Gred[pair][c][c']  (fp16 out)
    gemm_tn<64, 64, 16, 4, 4, float, __half><<<dim3(1, 8, 128), 256, 0, stream>>>(
        Wq, Gred, E16, 64, 512, 64, 64,
        1, 0LL, 1, 0LL,
        1, 4096LL, 1, 0LL,
        1, 32768LL, 1, 0LL);

    // rsp partial rowsums of exp(r*S)   (MFMA, plain stores)
    mfma_rows<<<dim3(4, 4, 128), 256, 0, stream>>>(E16, WkT16, sums2, rsp);

    // U2[db][j][o] = sum_i attn[i][j] * Wo[i][o]   (fused recompute, MFMA)
    mfma_su2<<<dim3(32, 16), 256, 0, stream>>>(E16, WkT16, Wo16, rsp, sums2, U2);

    // ZstT[db][o][bp*64+c] = sum_ch U2[db][bp*512+ch][o] * WvT[ch][c]
    gemm_tn<64, 64, 16, 4, 4, float, __half><<<dim3(1, 1, 128), 256, 0, stream>>>(
        U2, WvT, ZstT, 512, 64, 64, 512,
        8, 262144LL, 8, 32768LL,
        1, 0LL, 1, 0LL,
        8, 32768LL, 8, 64LL);

    // out[db][n][o] = sum_k emb_kv * ZstT   (MFMA f16, fp32 out)
    mfma_out<<<dim3(16, 16), 256, 0, stream>>>(emb, ZstT, out);
}

// Round 13
// 165.586 us; speedup vs baseline: 1.4231x; 1.3011x over previous
//
#include <hip/hip_runtime.h>
#include <hip/hip_fp16.h>

#define EPS 1e-5f

typedef __attribute__((ext_vector_type(8))) _Float16 half8;
typedef __attribute__((ext_vector_type(4))) float float4v;

// ---------------------------------------------------------------------------
// TN GEMM (E16 production only): C[m][n] = sum_k A[k][m] * B[k][n]
// ---------------------------------------------------------------------------
template<int BM, int BN, int BK, int TM, int TN, typename TA, typename TC>
__global__ __launch_bounds__((BM/TM)*(BN/TN))
void gemm_tn(const TA* __restrict__ A, const float* __restrict__ B,
             TC* __restrict__ C, int K,
             int lda, int ldb, int ldc,
             int divA, long long bsAd, int modA, long long bsAm,
             int divB, long long bsBd, int modB, long long bsBm,
             int divC, long long bsCd, int modC, long long bsCm)
{
    constexpr int T  = (BM/TM)*(BN/TN);
    constexpr int HM = TM/2, HN = TN/2;
    __shared__ float As[BK][BM];
    __shared__ float Bs[BK][BN];

    const int tid = threadIdx.x;
    const int z = blockIdx.z;
    const int n0 = blockIdx.x * BN;
    const int m0 = blockIdx.y * BM;
    A += (long long)(z / divA) * bsAd + (long long)(z % modA) * bsAm;
    B += (long long)(z / divB) * bsBd + (long long)(z % modB) * bsBm;
    C += (long long)(z / divC) * bsCd + (long long)(z % modC) * bsCm;

    const int tx = tid % (BN/TN);
    const int ty = tid / (BN/TN);

    float acc[TM][TN] = {};

    for (int k0 = 0; k0 < K; k0 += BK) {
#pragma unroll
        for (int idx = tid * 4; idx < BK * BM; idx += T * 4) {
            int rr = idx / BM, cc = idx % BM;
            *(float4*)&As[rr][cc] = *(const float4*)(A + (long long)(k0 + rr) * lda + m0 + cc);
        }
#pragma unroll
        for (int idx = tid * 4; idx < BK * BN; idx += T * 4) {
            int rr = idx / BN, cc = idx % BN;
            *(float4*)&Bs[rr][cc] = *(const float4*)(B + (long long)(k0 + rr) * ldb + n0 + cc);
        }
        __syncthreads();
#pragma unroll
        for (int kk = 0; kk < BK; kk++) {
            float a[TM], b[TN];
#pragma unroll
            for (int u = 0; u < HM; u++) {
                a[u]      = As[kk][ty * HM + u];
                a[HM + u] = As[kk][BM / 2 + ty * HM + u];
            }
#pragma unroll
            for (int v = 0; v < HN; v++) {
                b[v]      = Bs[kk][tx * HN + v];
                b[HN + v] = Bs[kk][BN / 2 + tx * HN + v];
            }
#pragma unroll
            for (int u = 0; u < TM; u++)
#pragma unroll
                for (int v = 0; v < TN; v++)
                    acc[u][v] += a[u] * b[v];
        }
        __syncthreads();
    }

#pragma unroll
    for (int u = 0; u < TM; u++) {
        int rl = (u < HM) ? ty * HM + u : BM / 2 + ty * HM + (u - HM);
        TC* cr = C + (long long)(m0 + rl) * ldc + n0;
        if constexpr (sizeof(TC) == 2) {
#pragma unroll
            for (int v = 0; v < HN; v++) {
                cr[tx * HN + v]          = __float2half(acc[u][v]);
                cr[BN / 2 + tx * HN + v] = __float2half(acc[u][HN + v]);
            }
        } else {
#pragma unroll
            for (int v = 0; v < HN; v++) {
                cr[tx * HN + v] = acc[u][v];
                cr[BN / 2 + tx * HN + v] = acc[u][HN + v];
            }
        }
    }
}

__device__ __forceinline__ float rv_from(const float* sums2, int db)
{
    float s1 = 0.f, s2 = 0.f;
#pragma unroll
    for (int p = 0; p < 8; p++) {
        s1 += sums2[(db * 8 + p) * 2];
        s2 += sums2[(db * 8 + p) * 2 + 1];
    }
    const float inv = 1.f / 2097152.f;
    float mu = s1 * inv;
    float var = s2 * inv - mu * mu;
    return rsqrtf(var + EPS);
}

// ---------------------------------------------------------------------------
// Mega-prep (flat grid 552), no atomics / no pre-zeroing:
//  bid <512   : MFMA Gram partials, d=0 pairs ONLY (G[1,b,b'] = G[0,b',b]^T)
//  512..519   : WkT16 fp16 transpose
//  520..527   : Wo16[o][i] fp16
//  528..535   : Wv16 fp16 plain copy ([c][ch])
//  536..551   : GW/GQ partial Grams + wsum partials (plain per-slice stores)
// ---------------------------------------------------------------------------
__global__ __launch_bounds__(256)
void prep_k(const float* __restrict__ emb, const float* __restrict__ Wq,
            const float* __restrict__ Wk, const float* __restrict__ Wv,
            const float* __restrict__ Wo, float* __restrict__ Gpart,
            __half* __restrict__ WkT16, __half* __restrict__ Wo16,
            __half* __restrict__ Wv16, float* __restrict__ GWQpart,
            float* __restrict__ wsp)
{
    __shared__ __align__(16) char smem[18432];
    const int tid = threadIdx.x;
    const int bid = blockIdx.x;

    if (bid < 512) {
        __half (*As)[72] = (__half(*)[72])smem;
        __half (*Bs)[72] = (__half(*)[72])(smem + 9216);
        const int ks = bid >> 6;
        const int z6 = bid & 63;             // d=0 pair: b_q*8 + b_kv
        const int b  = z6 >> 3;
        const int bp = z6 & 7;
        const float* Xq  = emb + (long long)b * 131072;              // lower
        const float* Xkv = emb + 1048576 + (long long)bp * 131072;   // upper

        const int lane = tid & 63, w = tid >> 6, q = lane >> 4, l16 = lane & 15;
        const int tok = tid & 63;
        const int cg  = w * 16;

        float4v acc[4];
#pragma unroll
        for (int nt = 0; nt < 4; nt++) acc[nt] = (float4v)0.f;

        for (int t0 = ks * 256; t0 < ks * 256 + 256; t0 += 64) {
            const float* q4 = Xq  + (long long)(t0 + tok) * 64 + cg;
            const float* k4 = Xkv + (long long)(t0 + tok) * 64 + cg;
#pragma unroll
            for (int j = 0; j < 4; j++) {
                float4 v = *(const float4*)(q4 + j * 4);
                As[cg + j * 4 + 0][tok] = __float2half(v.x);
                As[cg + j * 4 + 1][tok] = __float2half(v.y);
                As[cg + j * 4 + 2][tok] = __float2half(v.z);
                As[cg + j * 4 + 3][tok] = __float2half(v.w);
                float4 u = *(const float4*)(k4 + j * 4);
                Bs[cg + j * 4 + 0][tok] = __float2half(u.x);
                Bs[cg + j * 4 + 1][tok] = __float2half(u.y);
                Bs[cg + j * 4 + 2][tok] = __float2half(u.z);
                Bs[cg + j * 4 + 3][tok] = __float2half(u.w);
            }
            __syncthreads();
#pragma unroll
            for (int kc = 0; kc < 64; kc += 32) {
                half8 af = *(const half8*)&As[w * 16 + l16][kc + q * 8];
                half8 bf[4];
#pragma unroll
                for (int nt = 0; nt < 4; nt++)
                    bf[nt] = *(const half8*)&Bs[nt * 16 + l16][kc + q * 8];
#pragma unroll
                for (int nt = 0; nt < 4; nt++)
                    acc[nt] = __builtin_amdgcn_mfma_f32_16x16x32_f16(af, bf[nt], acc[nt], 0, 0, 0);
            }
            __syncthreads();
        }

        float* Gz = Gpart + (long long)ks * 262144 + (long long)z6 * 4096;
#pragma unroll
        for (int nt = 0; nt < 4; nt++)
#pragma unroll
            for (int t = 0; t < 4; t++) {
                int m = w * 16 + q * 4 + t;
                Gz[m * 64 + nt * 16 + l16] = acc[nt][t];
            }
    } else if (bid < 528) {
        float (*t)[65] = (float(*)[65])smem;
        const int which = (bid - 512) >> 3;      // 0 WkT16, 1 Wo16
        const int c0 = ((bid - 512) & 7) * 64;
        const int c = tid & 63, r4 = tid >> 6;
        if (which == 0) {
#pragma unroll
            for (int rr = r4; rr < 64; rr += 4)
                t[rr][c] = Wk[rr * 512 + c0 + c];
            __syncthreads();
#pragma unroll
            for (int rr = r4; rr < 64; rr += 4)
                WkT16[(c0 + rr) * 64 + c] = __float2half(t[c][rr]);
        } else {
#pragma unroll
            for (int rr = r4; rr < 64; rr += 4)
                t[rr][c] = Wo[(c0 + rr) * 64 + c];
            __syncthreads();
#pragma unroll
            for (int rr = r4; rr < 64; rr += 4)
                Wo16[rr * 512 + c0 + c] = __float2half(t[c][rr]);
        }
    } else if (bid < 536) {
        // Wv16 plain fp16 copy [c][ch]
        const int base = (bid - 528) * 4096;
#pragma unroll
        for (int it = 0; it < 4; it++) {
            int e = base + (tid + it * 256) * 4;
            float4 v = *(const float4*)(Wv + e);
            *(__half2*)(Wv16 + e)     = __floats2half2_rn(v.x, v.y);
            *(__half2*)(Wv16 + e + 2) = __floats2half2_rn(v.z, v.w);
        }
    } else {
        float (*Wl)[68] = (float(*)[68])smem;
        const int t2 = bid - 536;
        const int which = t2 >> 3;               // 0 -> Wk/GW, 1 -> Wq/GQ
        const int sl = t2 & 7;
        const int i0 = sl * 64;
        const float* W = which ? Wq : Wk;
        float* Gout = GWQpart + (long long)(which * 8 + sl) * 4096;
#pragma unroll
        for (int it = 0; it < 4; it++) {
            int e = tid + it * 256;
            int cc = e >> 4, i4 = (e & 15) * 4;
            *(float4*)&Wl[cc][i4] = *(const float4*)(W + cc * 512 + i0 + i4);
        }
        __syncthreads();
        if (tid < 64) {
            float s = 0.f;
#pragma unroll
            for (int j = 0; j < 64; j++) s += Wl[tid][j];
            wsp[(which * 8 + sl) * 64 + tid] = s;
        }
        const int cr = tid >> 2, cg = (tid & 3) * 16;
        float p[16] = {};
        for (int k = 0; k < 64; k++) {
            float a = Wl[cr][k];
#pragma unroll
            for (int j = 0; j < 16; j++) p[j] += a * Wl[cg + j][k];
        }
#pragma unroll
        for (int j = 0; j < 16; j++)
            Gout[cr * 64 + cg + j] = p[j];
    }
}

// ---------------------------------------------------------------------------
// stats2: reduce Gpart (d=0 base, transpose for d=1), write logical Gred,
// reduce GW/GQ/wsum, analytic IN stats -> sums2. grid 128 pairs.
// ---------------------------------------------------------------------------
__global__ __launch_bounds__(256)
void stats2_k(const float* __restrict__ Gpart, const float* __restrict__ GWQpart,
              const float* __restrict__ wsp, float* __restrict__ Gred,
              float* __restrict__ sums2)
{
    __shared__ float Graw[64][68], Gs[64][68], GQs[64][68], GWs[64][68];
    __shared__ float wqsS[64], wksS[64];
    const int tid = threadIdx.x;
    const int z = blockIdx.x;
    const int d = z >> 6, b = (z >> 3) & 7, bp = z & 7;
    const int zm = d ? (bp * 8 + b) : (b * 8 + bp);

    for (int f = tid * 4; f < 4096; f += 1024) {
        float4 g = make_float4(0.f, 0.f, 0.f, 0.f);
        float4 gw = g, gq = g;
#pragma unroll
        for (int s = 0; s < 8; s++) {
            float4 p = *(const float4*)(Gpart + (long long)s * 262144 + (long long)zm * 4096 + f);
            g.x += p.x; g.y += p.y; g.z += p.z; g.w += p.w;
            float4 w1 = *(const float4*)(GWQpart + (long long)s * 4096 + f);
            gw.x += w1.x; gw.y += w1.y; gw.z += w1.z; gw.w += w1.w;
            float4 q1 = *(const float4*)(GWQpart + (long long)(8 + s) * 4096 + f);
            gq.x += q1.x; gq.y += q1.y; gq.z += q1.z; gq.w += q1.w;
        }
        int rr = f >> 6, cc = f & 63;
        *(float4*)&Graw[rr][cc] = g;
        *(float4*)&GWs[rr][cc] = gw;
        *(float4*)&GQs[rr][cc] = gq;
    }
    if (tid < 64) {
        float a = 0.f, bsum = 0.f;
#pragma unroll
        for (int s = 0; s < 8; s++) {
            bsum += wsp[s * 64 + tid];          // Wk sums
            a    += wsp[(8 + s) * 64 + tid];    // Wq sums
        }
        wqsS[tid] = a; wksS[tid] = bsum;
    }
    __syncthreads();
    // logical G (transpose for d=1)
    for (int e = tid; e < 4096; e += 256) {
        int rr = e >> 6, cc = e & 63;
        Gs[rr][cc] = d ? Graw[cc][rr] : Graw[rr][cc];
    }
    __syncthreads();
    for (int f = tid * 4; f < 4096; f += 1024)
        *(float4*)(Gred + (long long)z * 4096 + f) = *(float4*)&Gs[f >> 6][f & 63];

    const int r = tid >> 2;
    const int c0 = (tid & 3) * 16;
    float p1[16] = {}, p2[16] = {};
    for (int k = 0; k < 64; k++) {
        float gq = GQs[r][k], g = Gs[r][k];
#pragma unroll
        for (int j = 0; j < 16; j++) {
            p1[j] += gq * Gs[k][c0 + j];
            p2[j] += g  * GWs[k][c0 + j];
        }
    }
    float s2 = 0.f;
#pragma unroll
    for (int j = 0; j < 16; j++) s2 += p1[j] * p2[j];
    float s1 = 0.f;
    const float wq = wqsS[r];
#pragma unroll
    for (int j = 0; j < 16; j++) s1 += wq * Gs[r][c0 + j] * wksS[c0 + j];

    const int lane = tid & 63, w = tid >> 6;
#pragma unroll
    for (int off = 32; off; off >>= 1) {
        s1 += __shfl_down(s1, off, 64);
        s2 += __shfl_down(s2, off, 64);
    }
    __shared__ float r1[4], r2[4];
    if (lane == 0) { r1[w] = s1; r2[w] = s2; }
    __syncthreads();
    if (tid == 0) {
        sums2[z * 2]     = r1[0] + r1[1] + r1[2] + r1[3];
        sums2[z * 2 + 1] = r2[0] + r2[1] + r2[2] + r2[3];
    }
}

// ---------------------------------------------------------------------------
// Fused MS: per (pair z, i-tile of 128), loop ch-chunks of 64:
//   S[ch][i] = WkT16-tile x E-tile (MFMA)                  [S once, not twice]
//   exp -> Pt[i][ch] (row-contiguous; no swizzle needed) + rs accumulation
//   M[i][c'] += Pt x Wv16-tile (MFMA)
// Writes Mt[z][c'][i] (fp16, /4096; via LDS transpose) and rsp partials.
// grid (128 z, 4 it), block 256. LDS ~55 KB -> 2 blocks/CU.
// ---------------------------------------------------------------------------
__global__ __launch_bounds__(256)
void mfma_ms(const __half* __restrict__ E16, const __half* __restrict__ WkT16,
             const __half* __restrict__ Wv16, const float* __restrict__ sums2,
             float* __restrict__ rsp, __half* __restrict__ Mt)
{
    __shared__ __half Es[128][72];
    __shared__ __half Wks[64][72];
    __shared__ __half Wvs[64][72];
    __shared__ __half Pt[128][72];   // reused as MtS[64][144] at the end

    const int tid = threadIdx.x;
    const int z = blockIdx.x;
    const int it = blockIdx.y;
    const int db = z >> 3, bp = z & 7;
    const int i0base = it * 128;
    const __half* Ez = E16 + (long long)z * 32768 + (long long)i0base * 64;

#pragma unroll
    for (int k = 0; k < 4; k++) {
        int e = tid + k * 256;
        int row = e >> 3, c8 = (e & 7) * 8;
        *(half8*)&Es[row][c8] = *(const half8*)(Ez + row * 64 + c8);
    }

    const int lane = tid & 63, w = tid >> 6, q = lane >> 4, l16 = lane & 15;
    const float rv = rv_from(sums2, db);

    float4v macc[2][4];   // [mt2: i-group][nt2: c'-group]
#pragma unroll
    for (int a = 0; a < 2; a++)
#pragma unroll
        for (int b2 = 0; b2 < 4; b2++) macc[a][b2] = (float4v)0.f;
    float rsacc[2] = {0.f, 0.f};

    const int srow = tid >> 2, sc8 = (tid & 3) * 16;

    for (int ch0 = 0; ch0 < 512; ch0 += 64) {
        __syncthreads();
        *(half8*)&Wks[srow][sc8]     = *(const half8*)(WkT16 + (long long)(ch0 + srow) * 64 + sc8);
        *(half8*)&Wks[srow][sc8 + 8] = *(const half8*)(WkT16 + (long long)(ch0 + srow) * 64 + sc8 + 8);
        *(half8*)&Wvs[srow][sc8]     = *(const half8*)(Wv16 + (long long)srow * 512 + ch0 + sc8);
        *(half8*)&Wvs[srow][sc8 + 8] = *(const half8*)(Wv16 + (long long)srow * 512 + ch0 + sc8 + 8);
        __syncthreads();

        // S-mfma: m=ch (4 mt), n=i (2 nt per wave), k=c' (2 kc)
        float4v sacc[4][2];
#pragma unroll
        for (int a = 0; a < 4; a++)
#pragma unroll
            for (int b2 = 0; b2 < 2; b2++) sacc[a][b2] = (float4v)0.f;
#pragma unroll
        for (int kc = 0; kc < 64; kc += 32) {
            half8 af[4], bf[2];
#pragma unroll
            for (int mt = 0; mt < 4; mt++)
                af[mt] = *(const half8*)&Wks[mt * 16 + l16][kc + q * 8];
#pragma unroll
            for (int nt = 0; nt < 2; nt++)
                bf[nt] = *(const half8*)&Es[w * 32 + nt * 16 + l16][kc + q * 8];
#pragma unroll
            for (int mt = 0; mt < 4; mt++)
#pragma unroll
                for (int nt = 0; nt < 2; nt++)
                    sacc[mt][nt] = __builtin_amdgcn_mfma_f32_16x16x32_f16(af[mt], bf[nt], sacc[mt][nt], 0, 0, 0);
        }

        // exp -> Pt[i][ch] (lane: fixed i, 4 consecutive ch) + rs accum
#pragma unroll
        for (int nt = 0; nt < 2; nt++) {
            const int i = w * 32 + nt * 16 + l16;
#pragma unroll
            for (int mt = 0; mt < 4; mt++) {
                float e0 = __expf(rv * sacc[mt][nt][0]);
                float e1 = __expf(rv * sacc[mt][nt][1]);
                float e2 = __expf(rv * sacc[mt][nt][2]);
                float e3 = __expf(rv * sacc[mt][nt][3]);
                rsacc[nt] += e0 + e1 + e2 + e3;
                const int ch = mt * 16 + q * 4;
                *(__half2*)&Pt[i][ch]     = __floats2half2_rn(e0, e1);
                *(__half2*)&Pt[i][ch + 2] = __floats2half2_rn(e2, e3);
            }
        }
        __syncthreads();

        // M-mfma: m=i (2 mt2 per wave), n=c' (4 nt2), k=ch (2 kc)
#pragma unroll
        for (int kc = 0; kc < 64; kc += 32) {
            half8 af2[2], bf2[4];
#pragma unroll
            for (int mt2 = 0; mt2 < 2; mt2++)
                af2[mt2] = *(const half8*)&Pt[w * 32 + mt2 * 16 + l16][kc + q * 8];
#pragma unroll
            for (int nt2 = 0; nt2 < 4; nt2++)
                bf2[nt2] = *(const half8*)&Wvs[nt2 * 16 + l16][kc + q * 8];
#pragma unroll
            for (int mt2 = 0; mt2 < 2; mt2++)
#pragma unroll
                for (int nt2 = 0; nt2 < 4; nt2++)
                    macc[mt2][nt2] = __builtin_amdgcn_mfma_f32_16x16x32_f16(af2[mt2], bf2[nt2], macc[mt2][nt2], 0, 0, 0);
        }
    }

    // rs partials: reduce over q (lane bits 4,5), store per (i, bp)
#pragma unroll
    for (int nt = 0; nt < 2; nt++) {
        float p = rsacc[nt];
        p += __shfl_xor(p, 16, 64);
        p += __shfl_xor(p, 32, 64);
        if (q == 0)
            rsp[(long long)(db * 512 + i0base + w * 32 + nt * 16 + l16) * 8 + bp] = p;
    }
    __syncthreads();   // protect Pt before reuse

    // Mt store: macc -> MtS[c'][i] (LDS) -> coalesced global [c'][i0base..+128]
    __half (*MtS)[144] = (__half(*)[144])&Pt[0][0];
    const float sc = 1.f / 4096.f;
#pragma unroll
    for (int mt2 = 0; mt2 < 2; mt2++)
#pragma unroll
        for (int nt2 = 0; nt2 < 4; nt2++) {
            const int cp = nt2 * 16 + l16;
            const int il = w * 32 + mt2 * 16 + q * 4;
#pragma unroll
            for (int t = 0; t < 4; t++)
                MtS[cp][il + t] = __float2half(macc[mt2][nt2][t] * sc);
        }
    __syncthreads();
    __half* Mz = Mt + (long long)z * 32768;
    {
        const int row = tid >> 2, seg = (tid & 3) * 32;
#pragma unroll
        for (int j = 0; j < 4; j++)
            *(half8*)(Mz + (long long)row * 512 + i0base + seg + j * 8) =
                *(const half8*)&MtS[row][seg + j * 8];
    }
}

// ---------------------------------------------------------------------------
// N gemm: NT[db][o][bp*64+c'] = sum_i Mt[z][c'][i]*(4096/rs[db][i])*Wo16[o][i]
// m=c', n=o (1 nt/wave), K=512. grid 128 (db*8+bp), block 256.
// ---------------------------------------------------------------------------
__global__ __launch_bounds__(256)
void mfma_n(const __half* __restrict__ Mt, const __half* __restrict__ Wo16,
            const float* __restrict__ rsp, __half* __restrict__ NT)
{
    __shared__ __half Mts[64][72];
    __shared__ __half Wos[64][72];
    __shared__ float invrS[64];
    const int tid = threadIdx.x;
    const int db = blockIdx.x >> 3, bp = blockIdx.x & 7;
    const __half* Mz = Mt + (long long)(db * 8 + bp) * 32768;
    const int lane = tid & 63, w = tid >> 6, q = lane >> 4, l16 = lane & 15;

    float4v acc[4];
#pragma unroll
    for (int mt = 0; mt < 4; mt++) acc[mt] = (float4v)0.f;

    const int srow = tid >> 2, sc8 = (tid & 3) * 16;

    for (int i0 = 0; i0 < 512; i0 += 64) {
        __syncthreads();
        if (tid < 64) {
            const float* rp = rsp + (long long)(db * 512 + i0 + tid) * 8;
            float4 a = *(const float4*)rp;
            float4 b = *(const float4*)(rp + 4);
            invrS[tid] = 4096.0f / (a.x + a.y + a.z + a.w + b.x + b.y + b.z + b.w);
        }
        __syncthreads();
#pragma unroll
        for (int h = 0; h < 2; h++) {
            half8 v = *(const half8*)(Mz + (long long)srow * 512 + i0 + sc8 + h * 8);
            half8 o;
#pragma unroll
            for (int j = 0; j < 8; j++)
                o[j] = (_Float16)((float)v[j] * invrS[sc8 + h * 8 + j]);
            *(half8*)&Mts[srow][sc8 + h * 8] = o;
            *(half8*)&Wos[srow][sc8 + h * 8] =
                *(const half8*)(Wo16 + (long long)srow * 512 + i0 + sc8 + h * 8);
        }
        __syncthreads();
#pragma unroll
        for (int kc = 0; kc < 64; kc += 32) {
            half8 af[4];
#pragma unroll
            for (int mt = 0; mt < 4; mt++)
                af[mt] = *(const half8*)&Mts[mt * 16 + l16][kc + q * 8];
            half8 bf = *(const half8*)&Wos[w * 16 + l16][kc + q * 8];
#pragma unroll
            for (int mt = 0; mt < 4; mt++)
                acc[mt] = __builtin_amdgcn_mfma_f32_16x16x32_f16(af[mt], bf, acc[mt], 0, 0, 0);
        }
    }

    __half* Nz = NT + (long long)db * 32768;
    const int o = w * 16 + l16;
#pragma unroll
    for (int mt = 0; mt < 4; mt++) {
        const int k = bp * 64 + mt * 16 + q * 4;
        *(__half2*)(Nz + (long long)o * 512 + k)     = __floats2half2_rn(acc[mt][0], acc[mt][1]);
        *(__half2*)(Nz + (long long)o * 512 + k + 2) = __floats2half2_rn(acc[mt][2], acc[mt][3]);
    }
}

// ---------------------------------------------------------------------------
// MFMA out:  out[db][n][o] = sum_{bp,c} emb_kv[bp][n][c] * NT[db][o][bp*64+c]
// ---------------------------------------------------------------------------
__global__ __launch_bounds__(256)
void mfma_out(const float* __restrict__ emb, const __half* __restrict__ NT,
              float* __restrict__ out)
{
    __shared__ __half Xs[128][72];
    __shared__ __half Bs[64][72];
    const int tid = threadIdx.x;
    const int db = blockIdx.y;
    const int d = db >> 3;
    const int n0 = blockIdx.x * 128;
    const float* Xb = emb + (long long)(1 - d) * 1048576;
    const __half* Bz = NT + (long long)db * 32768;

    const int lane = tid & 63, w = tid >> 6, q = lane >> 4, l16 = lane & 15;

    float4v acc[2][4];
#pragma unroll
    for (int a = 0; a < 2; a++)
#pragma unroll
        for (int b = 0; b < 4; b++) acc[a][b] = (float4v)0.f;

    for (int bp = 0; bp < 8; bp++) {
        const float* src = Xb + (long long)bp * 131072 + (long long)n0 * 64;
#pragma unroll
        for (int it = 0; it < 8; it++) {
            int e = (tid + it * 256) * 4;
            int row = e >> 6, col = e & 63;
            float4 v = *(const float4*)(src + (long long)row * 64 + col);
            *(__half2*)&Xs[row][col]     = __floats2half2_rn(v.x, v.y);
            *(__half2*)&Xs[row][col + 2] = __floats2half2_rn(v.z, v.w);
        }
        {
            int o = tid >> 2, c8 = (tid & 3) * 16;
            *(half8*)&Bs[o][c8]     = *(const half8*)(Bz + o * 512 + bp * 64 + c8);
            *(half8*)&Bs[o][c8 + 8] = *(const half8*)(Bz + o * 512 + bp * 64 + c8 + 8);
        }
        __syncthreads();
#pragma unroll
        for (int kc = 0; kc < 64; kc += 32) {
            half8 af[2], bf[4];
#pragma unroll
            for (int mt = 0; mt < 2; mt++)
                af[mt] = *(const half8*)&Xs[w * 32 + mt * 16 + l16][kc + q * 8];
#pragma unroll
            for (int ot = 0; ot < 4; ot++)
                bf[ot] = *(const half8*)&Bs[ot * 16 + l16][kc + q * 8];
#pragma unroll
            for (int mt = 0; mt < 2; mt++)
#pragma unroll
                for (int ot = 0; ot < 4; ot++)
                    acc[mt][ot] = __builtin_amdgcn_mfma_f32_16x16x32_f16(af[mt], bf[ot], acc[mt][ot], 0, 0, 0);
        }
        __syncthreads();
    }

    float* Od = out + (long long)db * 131072;
#pragma unroll
    for (int mt = 0; mt < 2; mt++)
#pragma unroll
        for (int ot = 0; ot < 4; ot++)
#pragma unroll
            for (int t = 0; t < 4; t++) {
                int n = n0 + w * 32 + mt * 16 + q * 4 + t;
                Od[(long long)n * 64 + ot * 16 + l16] = acc[mt][ot][t];
            }
}

// ---------------------------------------------------------------------------
// Workspace (float offsets, no zero-init anywhere):
//   Gpart @0: 2097152 (8 slices x 64 d=0 pairs x 4096) -> 2097152
//   GWQpart @2097152: 65536 | wsp @2162688: 1024 | sums2 @2163712: 256
//   Gred @2163968: 524288 -> 2688256
//   rsp @2688256: 65536 -> 2753792      ((db*512+i)*8 + bp)
//   E16 (half) @2753792: 4194304 h -> 4850944
//   WkT16 (half) @4850944 -> 4867328 | Wv16 @4867328 -> 4883712
//   Wo16 @4883712 -> 4900096
//   Mt (half) @4900096: 4194304 h -> 6997248   ([z][c'][i])
//   NT (half) @6997248: 524288 h -> 7259392    ([db][o][k])
// ---------------------------------------------------------------------------
extern "C" void kernel_launch(void* const* d_in, const int* in_sizes, int n_in,
                              void* d_out, int out_size, void* d_ws, size_t ws_size,
                              hipStream_t stream)
{
    const float* emb = (const float*)d_in[0];
    const float* Wq  = (const float*)d_in[1];
    const float* Wk  = (const float*)d_in[2];
    const float* Wv  = (const float*)d_in[3];
    const float* Wo  = (const float*)d_in[4];
    float* out = (float*)d_out;
    float* ws  = (float*)d_ws;

    float* Gpart   = ws;
    float* GWQpart = ws + 2097152;
    float* wsp     = ws + 2162688;
    float* sums2   = ws + 2163712;
    float* Gred    = ws + 2163968;
    float* rsp     = ws + 2688256;
    __half* E16    = (__half*)(ws + 2753792);
    __half* WkT16  = (__half*)(ws + 4850944);
    __half* Wv16   = (__half*)(ws + 4867328);
    __half* Wo16   = (__half*)(ws + 4883712);
    __half* Mt     = (__half*)(ws + 4900096);
    __half* NT     = (__half*)(ws + 6997248);

    // Gram partials (d=0 only) + weight prep + GW/GQ/wsum partials
    prep_k<<<552, 256, 0, stream>>>(emb, Wq, Wk, Wv, Wo, Gpart, WkT16, Wo16,
                                    Wv16, GWQpart, wsp);

    // reduce partials (+transpose for d=1) + analytic IN stats
    stats2_k<<<128, 256, 0, stream>>>(Gpart, GWQpart, wsp, Gred, sums2);

    // E16[pair][i][c'] = sum_c Wq[c][i] * Gred[pair][c][c']  (fp16 out)
    gemm_tn<64, 64, 16, 4, 4, float, __half><<<dim3(1, 8, 128), 256, 0, stream>>>(
        Wq, Gred, E16, 64, 512, 64, 64,
        1, 0LL, 1, 0LL,
        1, 4096LL, 1, 0LL,
        1, 32768LL, 1, 0LL);

    // fused S + exp + V-contraction (S computed once; rs fused)
    mfma_ms<<<dim3(128, 4), 256, 0, stream>>>(E16, WkT16, Wv16, sums2, rsp, Mt);

    // NT[db][o][k] = sum_i (Mt/rs) * Wo   (softmax normalization folded here)
    mfma_n<<<128, 256, 0, stream>>>(Mt, Wo16, rsp, NT);

    // out[db][n][o] = sum_k emb_kv * NT   (MFMA f16, fp32 out)
    mfma_out<<<dim3(16, 16), 256, 0, stream>>>(emb, NT, out);
}